// Round 7
// baseline (551.533 us; speedup 1.0000x reference)
//
#include <hip/hip_runtime.h>
#include <hip/hip_bf16.h>

typedef unsigned short u16;
typedef unsigned int u32;
typedef __attribute__((ext_vector_type(8))) short bf16x8;
typedef __attribute__((ext_vector_type(4))) float f32x4;

#define D_MODEL 2048
#define N_HEADS 16
#define HEAD_DIM 128
#define SEQ 2048
#define BATCH 2
#define M_ROWS (BATCH * SEQ)   // 4096

__device__ __forceinline__ u16 f2bf(float f) {
  union { float f; u32 u; } x; x.f = f;
  u32 r = x.u + 0x7fffu + ((x.u >> 16) & 1u);
  return (u16)(r >> 16);
}
__device__ __forceinline__ float bf2f(u16 h) {
  union { u32 u; float f; } x; x.u = ((u32)h) << 16;
  return x.f;
}

__device__ __forceinline__ void async_copy16(void* lds, const void* gptr) {
  __builtin_amdgcn_global_load_lds(
      (const __attribute__((address_space(1))) void*)gptr,
      (__attribute__((address_space(3))) void*)lds, 16, 0, 0);
}

// ---------------- elementwise cast f32 -> bf16 ----------------
__global__ __launch_bounds__(256) void cast_bf16_kernel(const float* __restrict__ in,
                                                        u16* __restrict__ out, int n4) {
  int i = blockIdx.x * blockDim.x + threadIdx.x;
  if (i >= n4) return;
  float4 v = reinterpret_cast<const float4*>(in)[i];
  ushort4 o;
  o.x = f2bf(v.x); o.y = f2bf(v.y); o.z = f2bf(v.z); o.w = f2bf(v.w);
  reinterpret_cast<ushort4*>(out)[i] = o;
}

// ---------------- RoPE cos/sin table ----------------
__global__ __launch_bounds__(256) void rope_table_kernel(float* __restrict__ cosT,
                                                         float* __restrict__ sinT) {
  int idx = blockIdx.x * blockDim.x + threadIdx.x;  // SEQ*64
  int s = idx >> 6, i = idx & 63;
  float invf = powf(10000.0f, -((float)(2 * i)) / 128.0f);
  float ang = (float)s * invf;
  cosT[idx] = cosf(ang);
  sinT[idx] = sinf(ang);
}

// ---------------- RoPE apply in-place on bf16 [bh][s][128] ----------------
// Q additionally prescaled by (1/sqrt(128))*log2(e): attn scores come out of
// QK^T already in log2 units -> exp2 directly, no per-score multiply.
__global__ __launch_bounds__(256) void rope_apply_kernel(u16* __restrict__ Q, u16* __restrict__ K,
                                                         const float* __restrict__ cosT,
                                                         const float* __restrict__ sinT) {
  const float PSC = 0.08838834764831845f * 1.4426950408889634f;
  int idx = blockIdx.x * blockDim.x + threadIdx.x;  // 32*2048*64
  u16* X = blockIdx.y ? K : Q;
  float scl = blockIdx.y ? 1.0f : PSC;
  int i = idx & 63;
  int s = (idx >> 6) & (SEQ - 1);
  float c = cosT[(s << 6) + i], sn = sinT[(s << 6) + i];
  size_t base = ((size_t)(idx >> 17) * SEQ + s) * HEAD_DIM;
  float x1 = bf2f(X[base + i]);
  float x2 = bf2f(X[base + i + 64]);
  X[base + i] = f2bf((x1 * c - x2 * sn) * scl);
  X[base + i + 64] = f2bf((x2 * c + x1 * sn) * scl);
}

// ---------------- V transpose: [bh][s][d] -> [bh][d][s] ----------------
__global__ __launch_bounds__(256) void vtrans_kernel(const u16* __restrict__ V,
                                                     u16* __restrict__ Vt) {
  __shared__ u16 t[64][72];
  int bh = blockIdx.z, s0 = blockIdx.x * 64, d0 = blockIdx.y * 64;
  int tid = threadIdx.x;
#pragma unroll
  for (int p = 0; p < 2; ++p) {
    int r = p * 32 + (tid >> 3), c8 = tid & 7;
    *(uint4*)&t[r][c8 * 8] =
        *(const uint4*)&V[((size_t)bh * SEQ + s0 + r) * HEAD_DIM + d0 + c8 * 8];
  }
  __syncthreads();
#pragma unroll
  for (int p = 0; p < 2; ++p) {
    int d = p * 32 + (tid >> 3), s8 = tid & 7;
    u16 tmp[8];
#pragma unroll
    for (int j = 0; j < 8; ++j) tmp[j] = t[s8 * 8 + j][d];
    *(uint4*)&Vt[((size_t)bh * HEAD_DIM + d0 + d) * SEQ + s0 + s8 * 8] = *(uint4*)tmp;
  }
}

// ---------------- GEMM: C[M,N] = A[M,K] * B[N,K]^T (both K-major bf16) ----------------
// MODE 0: QKV projection, writes bf16 [b][h][s][d] per blockIdx.z {Q,K,V}
// MODE 1: output projection, writes fp32 [m][n]
template <int MODE>
__global__ __launch_bounds__(256) void gemm_bt_kernel(
    const u16* __restrict__ A, const u16* __restrict__ B0, const u16* __restrict__ B1,
    const u16* __restrict__ B2, u16* __restrict__ Y0, u16* __restrict__ Y1,
    u16* __restrict__ Y2, float* __restrict__ OUT) {
  constexpr int KD = 2048;
  __shared__ u16 As[128 * 64];
  __shared__ u16 Bs[128 * 64];
  const int m0 = blockIdx.x * 128;
  const int n0 = blockIdx.y * 128;
  const u16* B = B0;
  u16* Y = Y0;
  if (MODE == 0) {
    if (blockIdx.z == 1) { B = B1; Y = Y1; }
    else if (blockIdx.z == 2) { B = B2; Y = Y2; }
  }
  const int tid = threadIdx.x;
  const int w = tid >> 6, l = tid & 63;
  const int wr = w >> 1, wc = w & 1;
  const int lrow = l & 15, lgrp = l >> 4;
  const int srow_in = l >> 3;
  const int sgcol = (((l & 7) ^ (l >> 3)) * 8);  // XOR-swizzled source column (bank fix)

  f32x4 acc[4][4];
#pragma unroll
  for (int mi = 0; mi < 4; ++mi)
#pragma unroll
    for (int ni = 0; ni < 4; ++ni) acc[mi][ni] = f32x4{0.f, 0.f, 0.f, 0.f};

  const u16* Ap = A + (size_t)m0 * KD;
  const u16* Bp = B + (size_t)n0 * KD;

  for (int k0 = 0; k0 < KD; k0 += 64) {
#pragma unroll
    for (int p = 0; p < 4; ++p) {
      int ig = w * 4 + p;
      int row = ig * 8 + srow_in;
      async_copy16(&As[ig * 512], &Ap[(size_t)row * KD + k0 + sgcol]);
      async_copy16(&Bs[ig * 512], &Bp[(size_t)row * KD + k0 + sgcol]);
    }
    __syncthreads();
#pragma unroll
    for (int ks = 0; ks < 2; ++ks) {
      bf16x8 af[4], bfr[4];
#pragma unroll
      for (int mi = 0; mi < 4; ++mi) {
        int row = wr * 64 + mi * 16 + lrow;
        int u = (ks * 4 + lgrp) ^ (row & 7);
        af[mi] = *(const bf16x8*)&As[row * 64 + u * 8];
      }
#pragma unroll
      for (int ni = 0; ni < 4; ++ni) {
        int row = wc * 64 + ni * 16 + lrow;
        int u = (ks * 4 + lgrp) ^ (row & 7);
        bfr[ni] = *(const bf16x8*)&Bs[row * 64 + u * 8];
      }
#pragma unroll
      for (int mi = 0; mi < 4; ++mi)
#pragma unroll
        for (int ni = 0; ni < 4; ++ni)
          acc[mi][ni] =
              __builtin_amdgcn_mfma_f32_16x16x32_bf16(af[mi], bfr[ni], acc[mi][ni], 0, 0, 0);
    }
    __syncthreads();
  }

#pragma unroll
  for (int mi = 0; mi < 4; ++mi)
#pragma unroll
    for (int ni = 0; ni < 4; ++ni)
#pragma unroll
      for (int r = 0; r < 4; ++r) {
        int m = m0 + wr * 64 + mi * 16 + lgrp * 4 + r;
        int n = n0 + wc * 64 + ni * 16 + lrow;
        if (MODE == 0) {
          int b = m >> 11, s = m & (SEQ - 1), h = n >> 7, d = n & 127;
          Y[(((size_t)b * N_HEADS + h) * SEQ + s) * HEAD_DIM + d] = f2bf(acc[mi][ni][r]);
        } else {
          OUT[(size_t)m * D_MODEL + n] = acc[mi][ni][r];
        }
      }
}

// ---------------- flash attention, FULL CAUSAL, split-K ----------------
// Block (p, hf, bh): q-tiles {p, 31-p}, K-half hf. Each block: 16-17 K-tile iters.
// Emits UNNORMALIZED O_hat (bf16) + per-row (m, l) f32; merge kernel combines halves.
// Q prescaled by SCALE*log2(e) -> scores are log2-units, exp2 directly.
// LDS: Ks 16KB + Vs 16KB, Ps aliased INTO Ks (Ks idle during softmax/PV; extra
// barrier after QK makes it safe) -> 32KB -> 4 blocks/CU, 16 waves/CU.
__global__ __launch_bounds__(256) void attn_split_kernel(
    const u16* __restrict__ Q, const u16* __restrict__ Kg, const u16* __restrict__ Vt,
    u16* __restrict__ OpH0, u16* __restrict__ OpH1, float2* __restrict__ Ml) {
  __shared__ u16 Ks[64 * 128];  // [k-row][d], 16B-granule XOR swizzle: g^(row&7)
  __shared__ u16 Vs[128 * 64];  // [d][k],   16B-granule XOR swizzle: g^(row&7)
  const int pr = blockIdx.x, hf = blockIdx.y, bh = blockIdx.z;
  const int tid = threadIdx.x;
  const int w = tid >> 6, l = tid & 63;
  const int lrow = l & 15, lgrp = l >> 4;
  const float NEG_INF = -__builtin_huge_valf();
  u16* Ps_w = &Ks[w * 1152];  // per-wave [16][72] u16 (2304B), 4 waves = 9216B < 16KB

  const int krow = tid >> 4, kcg = tid & 15;
  const int vrow = tid >> 3, vcg = tid & 7;

  const u16* Kbase = Kg + (size_t)bh * SEQ * HEAD_DIM;
  const u16* Vbase = Vt + (size_t)bh * HEAD_DIM * SEQ;

  for (int pass = 0; pass < 2; ++pass) {
    const int qi = pass ? (31 - pr) : pr;
    const int q0 = qi * 64;
    const int nt = qi + 1;
    const int n0 = (nt + 1) >> 1;
    const int tb = hf ? n0 : 0;
    const int te = hf ? nt : n0;

    bf16x8 qf[4];
    {
      size_t qbase = ((size_t)bh * SEQ + q0 + w * 16 + lrow) * HEAD_DIM;
#pragma unroll
      for (int c = 0; c < 4; ++c) qf[c] = *(const bf16x8*)&Q[qbase + c * 32 + lgrp * 8];
    }
    f32x4 oacc[8];
#pragma unroll
    for (int dt = 0; dt < 8; ++dt) oacc[dt] = f32x4{0.f, 0.f, 0.f, 0.f};
    float mrun[4], lrun[4];
#pragma unroll
    for (int r = 0; r < 4; ++r) { mrun[r] = -1e30f; lrun[r] = 0.f; }

    uint4 kreg[4], vreg[4];
    if (tb < te) {  // prologue: tile tb -> regs -> LDS
      const int kb = tb * 64;
#pragma unroll
      for (int p = 0; p < 4; ++p)
        kreg[p] = *(const uint4*)&Kbase[(size_t)(kb + p * 16 + krow) * HEAD_DIM + kcg * 8];
#pragma unroll
      for (int p = 0; p < 4; ++p)
        vreg[p] = *(const uint4*)&Vbase[(size_t)(p * 32 + vrow) * SEQ + kb + vcg * 8];
#pragma unroll
      for (int p = 0; p < 4; ++p) {
        int r = p * 16 + krow;
        int pg = (kcg & 8) | ((kcg ^ r) & 7);
        *(uint4*)&Ks[r * 128 + pg * 8] = kreg[p];
      }
#pragma unroll
      for (int p = 0; p < 4; ++p) {
        int r = p * 32 + vrow;
        int pg = (vcg ^ r) & 7;
        *(uint4*)&Vs[r * 64 + pg * 8] = vreg[p];
      }
      __syncthreads();
    }

    for (int t = tb; t < te; ++t) {
      const int k0 = t * 64;
      const bool have_next = (t + 1) < te;
      if (have_next) {  // T14: issue next-tile loads early
        const int kn = k0 + 64;
#pragma unroll
        for (int p = 0; p < 4; ++p)
          kreg[p] = *(const uint4*)&Kbase[(size_t)(kn + p * 16 + krow) * HEAD_DIM + kcg * 8];
#pragma unroll
        for (int p = 0; p < 4; ++p)
          vreg[p] = *(const uint4*)&Vbase[(size_t)(p * 32 + vrow) * SEQ + kn + vcg * 8];
      }

      f32x4 sc[4];
      __builtin_amdgcn_s_setprio(1);
#pragma unroll
      for (int kt = 0; kt < 4; ++kt) {
        f32x4 a = f32x4{0.f, 0.f, 0.f, 0.f};
#pragma unroll
        for (int c = 0; c < 4; ++c) {
          int r = kt * 16 + lrow;
          int g = c * 4 + lgrp;
          int pg = (g & 8) | ((g ^ r) & 7);
          bf16x8 kf = *(const bf16x8*)&Ks[r * 128 + pg * 8];
          a = __builtin_amdgcn_mfma_f32_16x16x32_bf16(qf[c], kf, a, 0, 0, 0);
        }
        sc[kt] = a;
      }
      __builtin_amdgcn_s_setprio(0);
      __syncthreads();  // all waves done reading Ks -> Ps alias region writable

      const bool bdry = (t == nt - 1);  // diagonal tile
#pragma unroll
      for (int kt = 0; kt < 4; ++kt)
#pragma unroll
        for (int r = 0; r < 4; ++r) {
          float s = sc[kt][r];
          if (bdry) {
            int j = k0 + kt * 16 + lrow;
            int i = q0 + w * 16 + lgrp * 4 + r;
            if (j > i) s = NEG_INF;
          }
          sc[kt][r] = s;
        }
      float resc[4], psum[4];
#pragma unroll
      for (int r = 0; r < 4; ++r) {
        float v = fmaxf(fmaxf(sc[0][r], sc[1][r]), fmaxf(sc[2][r], sc[3][r]));
        v = fmaxf(v, __shfl_xor(v, 1));
        v = fmaxf(v, __shfl_xor(v, 2));
        v = fmaxf(v, __shfl_xor(v, 4));
        v = fmaxf(v, __shfl_xor(v, 8));
        float mnew = fmaxf(mrun[r], v);
        resc[r] = exp2f(mrun[r] - mnew);
        mrun[r] = mnew;
        psum[r] = 0.f;
      }
#pragma unroll
      for (int kt = 0; kt < 4; ++kt)
#pragma unroll
        for (int r = 0; r < 4; ++r) {
          float p = exp2f(sc[kt][r] - mrun[r]);
          psum[r] += p;
          Ps_w[(lgrp * 4 + r) * 72 + kt * 16 + lrow] = f2bf(p);
        }
#pragma unroll
      for (int r = 0; r < 4; ++r) {
        float v = psum[r];
        v += __shfl_xor(v, 1);
        v += __shfl_xor(v, 2);
        v += __shfl_xor(v, 4);
        v += __shfl_xor(v, 8);
        lrun[r] = lrun[r] * resc[r] + v;
      }
#pragma unroll
      for (int dt = 0; dt < 8; ++dt)
#pragma unroll
        for (int r = 0; r < 4; ++r) oacc[dt][r] *= resc[r];
      bf16x8 pf[2];
#pragma unroll
      for (int kc = 0; kc < 2; ++kc)
        pf[kc] = *(const bf16x8*)&Ps_w[lrow * 72 + kc * 32 + lgrp * 8];
      __builtin_amdgcn_s_setprio(1);
#pragma unroll
      for (int dt = 0; dt < 8; ++dt) {
#pragma unroll
        for (int kc = 0; kc < 2; ++kc) {
          int r = dt * 16 + lrow;
          int g = kc * 4 + lgrp;
          int pg = (g ^ r) & 7;
          bf16x8 vf = *(const bf16x8*)&Vs[r * 64 + pg * 8];
          oacc[dt] = __builtin_amdgcn_mfma_f32_16x16x32_bf16(pf[kc], vf, oacc[dt], 0, 0, 0);
        }
      }
      __builtin_amdgcn_s_setprio(0);
      __syncthreads();  // all waves done with Vs + Ps(alias in Ks)
      if (have_next) {
#pragma unroll
        for (int p = 0; p < 4; ++p) {
          int r = p * 16 + krow;
          int pg = (kcg & 8) | ((kcg ^ r) & 7);
          *(uint4*)&Ks[r * 128 + pg * 8] = kreg[p];
        }
#pragma unroll
        for (int p = 0; p < 4; ++p) {
          int r = p * 32 + vrow;
          int pg = (vcg ^ r) & 7;
          *(uint4*)&Vs[r * 64 + pg * 8] = vreg[p];
        }
        __syncthreads();
      }
    }

    // epilogue: unnormalized partial O + (m, l)
    u16* Op = hf ? OpH1 : OpH0;
#pragma unroll
    for (int dt = 0; dt < 8; ++dt)
#pragma unroll
      for (int r = 0; r < 4; ++r) {
        int s = q0 + w * 16 + lgrp * 4 + r;
        Op[((size_t)bh * SEQ + s) * HEAD_DIM + dt * 16 + lrow] = f2bf(oacc[dt][r]);
      }
    if (lrow == 0) {
#pragma unroll
      for (int r = 0; r < 4; ++r) {
        int s = q0 + w * 16 + lgrp * 4 + r;
        Ml[hf * (32 * SEQ) + bh * SEQ + s] = float2{mrun[r], lrun[r]};
      }
    }
  }
}

// ---------------- merge two K-halves ----------------
// O = (w0*O_hat0 + w1*O_hat1) / (w0*l0 + w1*l1), wi = exp2(mi - max(m0,m1))
__global__ __launch_bounds__(256) void attn_merge_kernel(const u16* __restrict__ O0,
                                                         const u16* __restrict__ O1,
                                                         const float2* __restrict__ Ml,
                                                         u16* __restrict__ O) {
  const int tid = threadIdx.x;
  const int row = blockIdx.x * 16 + (tid >> 4);  // bh*2048 + s
  const int d = (tid & 15) * 8;
  float2 a = Ml[row];
  float2 c = Ml[32 * SEQ + row];
  float mx = fmaxf(a.x, c.x);
  float w0 = exp2f(a.x - mx), w1 = exp2f(c.x - mx);
  float inv = 1.0f / (w0 * a.y + w1 * c.y);
  w0 *= inv; w1 *= inv;
  size_t src = (size_t)row * HEAD_DIM + d;
  bf16x8 v0 = *(const bf16x8*)&O0[src];
  bf16x8 v1 = *(const bf16x8*)&O1[src];
  u16 outv[8];
#pragma unroll
  for (int j = 0; j < 8; ++j)
    outv[j] = f2bf(w0 * bf2f((u16)v0[j]) + w1 * bf2f((u16)v1[j]));
  int bh = row >> 11, s = row & (SEQ - 1);
  size_t dst = ((size_t)(bh >> 4) * SEQ + s) * D_MODEL + (bh & 15) * HEAD_DIM + d;
  *(uint4*)&O[dst] = *(uint4*)outv;
}

// ---------------- launch ----------------
extern "C" void kernel_launch(void* const* d_in, const int* in_sizes, int n_in,
                              void* d_out, int out_size, void* d_ws, size_t ws_size,
                              hipStream_t stream) {
  const float* X = (const float*)d_in[0];
  const float* Wq = (const float*)d_in[1];
  const float* Wk = (const float*)d_in[2];
  const float* Wv = (const float*)d_in[3];
  const float* Wo = (const float*)d_in[4];
  float* OUT = (float*)d_out;
  char* ws = (char*)d_ws;

  u16* Xb = (u16*)(ws);                       // 16 MB (-> Ob after attn)
  u16* Wb0 = (u16*)(ws + (16u << 20));        // 4x8 MB
  u16* Wb1 = Wb0 + 4194304;
  u16* Wb2 = Wb1 + 4194304;
  u16* Wb3 = Wb2 + 4194304;
  u16* Qb = (u16*)(ws + (48u << 20));         // 16 MB
  u16* Kb = (u16*)(ws + (64u << 20));         // 16 MB
  u16* Vb = (u16*)(ws + (80u << 20));         // 16 MB
  u16* Vt = (u16*)(ws + (96u << 20));         // 16 MB
  float* cosT = (float*)(ws + (112u << 20));  // 512 KB
  float* sinT = cosT + SEQ * 64;              // 512 KB
  u16* Ob = Xb;                               // alias: Xb dead after gemm_qkv
  // split-attn partials in dead regions:
  u16* OpH0 = Vb;                             // Vb dead after vtrans (16 MB)
  u16* OpH1 = Wb0;                            // Wb0+Wb1 dead after gemm<0> (16 MB)
  float2* Ml = (float2*)Wb2;                  // Wb2 dead after gemm<0> (2 MB used)

  cast_bf16_kernel<<<8192, 256, 0, stream>>>(X, Xb, (M_ROWS * D_MODEL) / 4);
  cast_bf16_kernel<<<4096, 256, 0, stream>>>(Wq, Wb0, (D_MODEL * D_MODEL) / 4);
  cast_bf16_kernel<<<4096, 256, 0, stream>>>(Wk, Wb1, (D_MODEL * D_MODEL) / 4);
  cast_bf16_kernel<<<4096, 256, 0, stream>>>(Wv, Wb2, (D_MODEL * D_MODEL) / 4);
  cast_bf16_kernel<<<4096, 256, 0, stream>>>(Wo, Wb3, (D_MODEL * D_MODEL) / 4);
  rope_table_kernel<<<512, 256, 0, stream>>>(cosT, sinT);

  gemm_bt_kernel<0><<<dim3(32, 16, 3), 256, 0, stream>>>(Xb, Wb0, Wb1, Wb2, Qb, Kb, Vb, nullptr);
  rope_apply_kernel<<<dim3(16384, 2), 256, 0, stream>>>(Qb, Kb, cosT, sinT);
  vtrans_kernel<<<dim3(32, 2, 32), 256, 0, stream>>>(Vb, Vt);
  attn_split_kernel<<<dim3(16, 2, 32), 256, 0, stream>>>(Qb, Kb, Vt, OpH0, OpH1, Ml);
  attn_merge_kernel<<<4096, 256, 0, stream>>>(OpH0, OpH1, Ml, Ob);
  gemm_bt_kernel<1><<<dim3(32, 16, 1), 256, 0, stream>>>(Ob, Wb3, nullptr, nullptr, nullptr,
                                                         nullptr, nullptr, OUT);
}

// Round 8
// 441.307 us; speedup vs baseline: 1.2498x; 1.2498x over previous
//
#include <hip/hip_runtime.h>
#include <hip/hip_bf16.h>

typedef unsigned short u16;
typedef unsigned int u32;
typedef __attribute__((ext_vector_type(8))) short bf16x8;
typedef __attribute__((ext_vector_type(4))) float f32x4;

#define D_MODEL 2048
#define N_HEADS 16
#define HEAD_DIM 128
#define SEQ 2048
#define BATCH 2
#define M_ROWS (BATCH * SEQ)   // 4096

__device__ __forceinline__ u16 f2bf(float f) {
  union { float f; u32 u; } x; x.f = f;
  u32 r = x.u + 0x7fffu + ((x.u >> 16) & 1u);
  return (u16)(r >> 16);
}
__device__ __forceinline__ float bf2f(u16 h) {
  union { u32 u; float f; } x; x.u = ((u32)h) << 16;
  return x.f;
}

__device__ __forceinline__ void async_copy16(void* lds, const void* gptr) {
  __builtin_amdgcn_global_load_lds(
      (const __attribute__((address_space(1))) void*)gptr,
      (__attribute__((address_space(3))) void*)lds, 16, 0, 0);
}

// ---------------- elementwise cast f32 -> bf16 ----------------
__global__ __launch_bounds__(256) void cast_bf16_kernel(const float* __restrict__ in,
                                                        u16* __restrict__ out, int n4) {
  int i = blockIdx.x * blockDim.x + threadIdx.x;
  if (i >= n4) return;
  float4 v = reinterpret_cast<const float4*>(in)[i];
  ushort4 o;
  o.x = f2bf(v.x); o.y = f2bf(v.y); o.z = f2bf(v.z); o.w = f2bf(v.w);
  reinterpret_cast<ushort4*>(out)[i] = o;
}

// ---------------- RoPE cos/sin table ----------------
__global__ __launch_bounds__(256) void rope_table_kernel(float* __restrict__ cosT,
                                                         float* __restrict__ sinT) {
  int idx = blockIdx.x * blockDim.x + threadIdx.x;  // SEQ*64
  int s = idx >> 6, i = idx & 63;
  float invf = powf(10000.0f, -((float)(2 * i)) / 128.0f);
  float ang = (float)s * invf;
  cosT[idx] = cosf(ang);
  sinT[idx] = sinf(ang);
}

// ---------------- RoPE apply in-place on bf16 [bh][s][128] ----------------
// Q additionally prescaled by (1/sqrt(128))*log2(e): attn scores come out of
// QK^T already in log2 units -> exp2 directly, no per-score multiply.
__global__ __launch_bounds__(256) void rope_apply_kernel(u16* __restrict__ Q, u16* __restrict__ K,
                                                         const float* __restrict__ cosT,
                                                         const float* __restrict__ sinT) {
  const float PSC = 0.08838834764831845f * 1.4426950408889634f;
  int idx = blockIdx.x * blockDim.x + threadIdx.x;  // 32*2048*64
  u16* X = blockIdx.y ? K : Q;
  float scl = blockIdx.y ? 1.0f : PSC;
  int i = idx & 63;
  int s = (idx >> 6) & (SEQ - 1);
  float c = cosT[(s << 6) + i], sn = sinT[(s << 6) + i];
  size_t base = ((size_t)(idx >> 17) * SEQ + s) * HEAD_DIM;
  float x1 = bf2f(X[base + i]);
  float x2 = bf2f(X[base + i + 64]);
  X[base + i] = f2bf((x1 * c - x2 * sn) * scl);
  X[base + i + 64] = f2bf((x2 * c + x1 * sn) * scl);
}

// ---------------- V transpose: [bh][s][d] -> [bh][d][s] ----------------
__global__ __launch_bounds__(256) void vtrans_kernel(const u16* __restrict__ V,
                                                     u16* __restrict__ Vt) {
  __shared__ u16 t[64][72];
  int bh = blockIdx.z, s0 = blockIdx.x * 64, d0 = blockIdx.y * 64;
  int tid = threadIdx.x;
#pragma unroll
  for (int p = 0; p < 2; ++p) {
    int r = p * 32 + (tid >> 3), c8 = tid & 7;
    *(uint4*)&t[r][c8 * 8] =
        *(const uint4*)&V[((size_t)bh * SEQ + s0 + r) * HEAD_DIM + d0 + c8 * 8];
  }
  __syncthreads();
#pragma unroll
  for (int p = 0; p < 2; ++p) {
    int d = p * 32 + (tid >> 3), s8 = tid & 7;
    u16 tmp[8];
#pragma unroll
    for (int j = 0; j < 8; ++j) tmp[j] = t[s8 * 8 + j][d];
    *(uint4*)&Vt[((size_t)bh * HEAD_DIM + d0 + d) * SEQ + s0 + s8 * 8] = *(uint4*)tmp;
  }
}

// ---------------- GEMM: C[M,N] = A[M,K] * B[N,K]^T (both K-major bf16) ----------------
// MODE 0: QKV projection, writes bf16 [b][h][s][d] per blockIdx.z {Q,K,V}
// MODE 1: output projection, writes fp32 [m][n]
template <int MODE>
__global__ __launch_bounds__(256) void gemm_bt_kernel(
    const u16* __restrict__ A, const u16* __restrict__ B0, const u16* __restrict__ B1,
    const u16* __restrict__ B2, u16* __restrict__ Y0, u16* __restrict__ Y1,
    u16* __restrict__ Y2, float* __restrict__ OUT) {
  constexpr int KD = 2048;
  __shared__ u16 As[128 * 64];
  __shared__ u16 Bs[128 * 64];
  const int m0 = blockIdx.x * 128;
  const int n0 = blockIdx.y * 128;
  const u16* B = B0;
  u16* Y = Y0;
  if (MODE == 0) {
    if (blockIdx.z == 1) { B = B1; Y = Y1; }
    else if (blockIdx.z == 2) { B = B2; Y = Y2; }
  }
  const int tid = threadIdx.x;
  const int w = tid >> 6, l = tid & 63;
  const int wr = w >> 1, wc = w & 1;
  const int lrow = l & 15, lgrp = l >> 4;
  const int srow_in = l >> 3;
  const int sgcol = (((l & 7) ^ (l >> 3)) * 8);  // XOR-swizzled source column (bank fix)

  f32x4 acc[4][4];
#pragma unroll
  for (int mi = 0; mi < 4; ++mi)
#pragma unroll
    for (int ni = 0; ni < 4; ++ni) acc[mi][ni] = f32x4{0.f, 0.f, 0.f, 0.f};

  const u16* Ap = A + (size_t)m0 * KD;
  const u16* Bp = B + (size_t)n0 * KD;

  for (int k0 = 0; k0 < KD; k0 += 64) {
#pragma unroll
    for (int p = 0; p < 4; ++p) {
      int ig = w * 4 + p;
      int row = ig * 8 + srow_in;
      async_copy16(&As[ig * 512], &Ap[(size_t)row * KD + k0 + sgcol]);
      async_copy16(&Bs[ig * 512], &Bp[(size_t)row * KD + k0 + sgcol]);
    }
    __syncthreads();
#pragma unroll
    for (int ks = 0; ks < 2; ++ks) {
      bf16x8 af[4], bfr[4];
#pragma unroll
      for (int mi = 0; mi < 4; ++mi) {
        int row = wr * 64 + mi * 16 + lrow;
        int u = (ks * 4 + lgrp) ^ (row & 7);
        af[mi] = *(const bf16x8*)&As[row * 64 + u * 8];
      }
#pragma unroll
      for (int ni = 0; ni < 4; ++ni) {
        int row = wc * 64 + ni * 16 + lrow;
        int u = (ks * 4 + lgrp) ^ (row & 7);
        bfr[ni] = *(const bf16x8*)&Bs[row * 64 + u * 8];
      }
#pragma unroll
      for (int mi = 0; mi < 4; ++mi)
#pragma unroll
        for (int ni = 0; ni < 4; ++ni)
          acc[mi][ni] =
              __builtin_amdgcn_mfma_f32_16x16x32_bf16(af[mi], bfr[ni], acc[mi][ni], 0, 0, 0);
    }
    __syncthreads();
  }

#pragma unroll
  for (int mi = 0; mi < 4; ++mi)
#pragma unroll
    for (int ni = 0; ni < 4; ++ni)
#pragma unroll
      for (int r = 0; r < 4; ++r) {
        int m = m0 + wr * 64 + mi * 16 + lgrp * 4 + r;
        int n = n0 + wc * 64 + ni * 16 + lrow;
        if (MODE == 0) {
          int b = m >> 11, s = m & (SEQ - 1), h = n >> 7, d = n & 127;
          Y[(((size_t)b * N_HEADS + h) * SEQ + s) * HEAD_DIM + d] = f2bf(acc[mi][ni][r]);
        } else {
          OUT[(size_t)m * D_MODEL + n] = acc[mi][ni][r];
        }
      }
}

// ---- K/V tile staging via global_load_lds: linear LDS dest + pre-swizzled
// global source (rule #21; sigma is an involution so the swizzled read
// composes to identity). 8 insts/wave = 1 K-subtile + 1 V-subtile. ----
__device__ __forceinline__ void stage_kv(const u16* __restrict__ Kbase,
                                         const u16* __restrict__ Vbase,
                                         u16* KsB, u16* VsB, int k0, int w, int l) {
#pragma unroll
  for (int p = 0; p < 4; ++p) {
    int row = w * 16 + p * 4 + (l >> 4);
    int g = l & 15;
    int sg = (g & 8) | ((g ^ row) & 7);
    async_copy16(&KsB[(w * 16 + p * 4) * 128],
                 &Kbase[(size_t)(k0 + row) * HEAD_DIM + sg * 8]);
  }
#pragma unroll
  for (int p = 0; p < 4; ++p) {
    int row = w * 32 + p * 8 + (l >> 3);
    int sg = ((l & 7) ^ row) & 7;
    async_copy16(&VsB[(w * 32 + p * 8) * 64],
                 &Vbase[(size_t)row * SEQ + k0 + sg * 8]);
  }
}

// ---------------- flash attention, FULL CAUSAL, split-K ----------------
// Grid (bh=32, pr=16, hf=2): bh is the FASTEST dim -> the 32 blocks sharing one
// bh's K/V are 32 apart in dispatch order -> all land on XCD bh%8 (L2 reuse).
// Block: q-tiles {pr, 31-pr}, K-half hf -> uniform ~17 K-tile iters.
// Staging: global_load_lds double-buffer, counted vmcnt(8) (never 0 mid-loop),
// raw s_barrier. No staging registers -> no scratch spill (r7 lesson: the
// uint4 prefetch arrays spilled 128B/thread/iter = 537MB of WRITE traffic).
// Emits unnormalized O_hat bf16 + (m,l) f32; merge kernel combines halves.
__global__ __launch_bounds__(256) void attn_split_kernel(
    const u16* __restrict__ Q, const u16* __restrict__ Kg, const u16* __restrict__ Vt,
    u16* __restrict__ OpH0, u16* __restrict__ OpH1, float2* __restrict__ Ml) {
  __shared__ u16 Ks[2][64 * 128];  // [k-row][d], 16B-granule XOR swizzle
  __shared__ u16 Vs[2][128 * 64];  // [d][k], 16B-granule XOR swizzle
  __shared__ u16 Ps[4][16 * 72];   // per-wave P tile, +8 pad
  const int bh = blockIdx.x, pr = blockIdx.y, hf = blockIdx.z;
  const int tid = threadIdx.x;
  const int w = tid >> 6, l = tid & 63;
  const int lrow = l & 15, lgrp = l >> 4;
  const float NEG_INF = -__builtin_huge_valf();
  u16* Ps_w = Ps[w];

  const u16* Kbase = Kg + (size_t)bh * SEQ * HEAD_DIM;
  const u16* Vbase = Vt + (size_t)bh * HEAD_DIM * SEQ;

  for (int pass = 0; pass < 2; ++pass) {
    const int qi = pass ? (31 - pr) : pr;
    const int q0 = qi * 64;
    const int nt = qi + 1;
    const int n0 = (nt + 1) >> 1;
    const int tb = hf ? n0 : 0;
    const int te = hf ? nt : n0;

    bf16x8 qf[4];
    {
      size_t qbase = ((size_t)bh * SEQ + q0 + w * 16 + lrow) * HEAD_DIM;
#pragma unroll
      for (int c = 0; c < 4; ++c) qf[c] = *(const bf16x8*)&Q[qbase + c * 32 + lgrp * 8];
    }
    f32x4 oacc[8];
#pragma unroll
    for (int dt = 0; dt < 8; ++dt) oacc[dt] = f32x4{0.f, 0.f, 0.f, 0.f};
    float mrun[4], lrun[4];
#pragma unroll
    for (int r = 0; r < 4; ++r) { mrun[r] = -1e30f; lrun[r] = 0.f; }

    // prologue: stage tile tb into buf 0 (async; waited at loop top)
    stage_kv(Kbase, Vbase, Ks[0], Vs[0], tb * 64, w, l);

    for (int t = tb; t < te; ++t) {
      const int k0 = t * 64;
      const int cur = (t - tb) & 1;
      const bool have_next = (t + 1) < te;
      if (have_next) {
        // buf[cur^1] was last read in iter t-1, which ended with s_barrier
        stage_kv(Kbase, Vbase, Ks[cur ^ 1], Vs[cur ^ 1], k0 + 64, w, l);
        asm volatile("s_waitcnt vmcnt(8)" ::: "memory");  // tile t landed; t+1 in flight
      } else {
        asm volatile("s_waitcnt vmcnt(0)" ::: "memory");
      }
      __builtin_amdgcn_s_barrier();  // all waves: buf[cur] ready

      const u16* Kc = Ks[cur];
      const u16* Vc = Vs[cur];

      f32x4 sc[4];
      __builtin_amdgcn_s_setprio(1);
#pragma unroll
      for (int kt = 0; kt < 4; ++kt) {
        f32x4 a = f32x4{0.f, 0.f, 0.f, 0.f};
#pragma unroll
        for (int c = 0; c < 4; ++c) {
          int r = kt * 16 + lrow;
          int g = c * 4 + lgrp;
          int pg = (g & 8) | ((g ^ r) & 7);
          bf16x8 kf = *(const bf16x8*)&Kc[r * 128 + pg * 8];
          a = __builtin_amdgcn_mfma_f32_16x16x32_bf16(qf[c], kf, a, 0, 0, 0);
        }
        sc[kt] = a;
      }
      __builtin_amdgcn_s_setprio(0);

      const bool bdry = (t == nt - 1);  // diagonal tile (only ever in hf=1's range)
#pragma unroll
      for (int kt = 0; kt < 4; ++kt)
#pragma unroll
        for (int r = 0; r < 4; ++r) {
          float s = sc[kt][r];
          if (bdry) {
            int j = k0 + kt * 16 + lrow;
            int i = q0 + w * 16 + lgrp * 4 + r;
            if (j > i) s = NEG_INF;
          }
          sc[kt][r] = s;
        }
      float resc[4], psum[4];
#pragma unroll
      for (int r = 0; r < 4; ++r) {
        float v = fmaxf(fmaxf(sc[0][r], sc[1][r]), fmaxf(sc[2][r], sc[3][r]));
        v = fmaxf(v, __shfl_xor(v, 1));
        v = fmaxf(v, __shfl_xor(v, 2));
        v = fmaxf(v, __shfl_xor(v, 4));
        v = fmaxf(v, __shfl_xor(v, 8));
        float mnew = fmaxf(mrun[r], v);
        resc[r] = exp2f(mrun[r] - mnew);
        mrun[r] = mnew;
        psum[r] = 0.f;
      }
#pragma unroll
      for (int kt = 0; kt < 4; ++kt)
#pragma unroll
        for (int r = 0; r < 4; ++r) {
          float p = exp2f(sc[kt][r] - mrun[r]);
          psum[r] += p;
          Ps_w[(lgrp * 4 + r) * 72 + kt * 16 + lrow] = f2bf(p);
        }
#pragma unroll
      for (int r = 0; r < 4; ++r) {
        float v = psum[r];
        v += __shfl_xor(v, 1);
        v += __shfl_xor(v, 2);
        v += __shfl_xor(v, 4);
        v += __shfl_xor(v, 8);
        lrun[r] = lrun[r] * resc[r] + v;
      }
#pragma unroll
      for (int dt = 0; dt < 8; ++dt)
#pragma unroll
        for (int r = 0; r < 4; ++r) oacc[dt][r] *= resc[r];
      // Ps is per-wave: within-wave ds ordering (lgkmcnt) suffices, no barrier.
      bf16x8 pf[2];
#pragma unroll
      for (int kc = 0; kc < 2; ++kc)
        pf[kc] = *(const bf16x8*)&Ps_w[lrow * 72 + kc * 32 + lgrp * 8];
      __builtin_amdgcn_s_setprio(1);
#pragma unroll
      for (int dt = 0; dt < 8; ++dt) {
#pragma unroll
        for (int kc = 0; kc < 2; ++kc) {
          int r = dt * 16 + lrow;
          int g = kc * 4 + lgrp;
          int pg = (g ^ r) & 7;
          bf16x8 vf = *(const bf16x8*)&Vc[r * 64 + pg * 8];
          oacc[dt] = __builtin_amdgcn_mfma_f32_16x16x32_bf16(pf[kc], vf, oacc[dt], 0, 0, 0);
        }
      }
      __builtin_amdgcn_s_setprio(0);
      __builtin_amdgcn_s_barrier();  // all waves done reading buf[cur]
    }

    // epilogue: unnormalized partial O + (m, l)
    u16* Op = hf ? OpH1 : OpH0;
#pragma unroll
    for (int dt = 0; dt < 8; ++dt)
#pragma unroll
      for (int r = 0; r < 4; ++r) {
        int s = q0 + w * 16 + lgrp * 4 + r;
        Op[((size_t)bh * SEQ + s) * HEAD_DIM + dt * 16 + lrow] = f2bf(oacc[dt][r]);
      }
    if (lrow == 0) {
#pragma unroll
      for (int r = 0; r < 4; ++r) {
        int s = q0 + w * 16 + lgrp * 4 + r;
        Ml[hf * (32 * SEQ) + bh * SEQ + s] = float2{mrun[r], lrun[r]};
      }
    }
  }
}

// ---------------- merge two K-halves ----------------
// O = (w0*O_hat0 + w1*O_hat1) / (w0*l0 + w1*l1), wi = exp2(mi - max(m0,m1))
__global__ __launch_bounds__(256) void attn_merge_kernel(const u16* __restrict__ O0,
                                                         const u16* __restrict__ O1,
                                                         const float2* __restrict__ Ml,
                                                         u16* __restrict__ O) {
  const int tid = threadIdx.x;
  const int row = blockIdx.x * 16 + (tid >> 4);  // bh*2048 + s
  const int d = (tid & 15) * 8;
  float2 a = Ml[row];
  float2 c = Ml[32 * SEQ + row];
  float mx = fmaxf(a.x, c.x);
  float w0 = exp2f(a.x - mx), w1 = exp2f(c.x - mx);
  float inv = 1.0f / (w0 * a.y + w1 * c.y);
  w0 *= inv; w1 *= inv;
  size_t src = (size_t)row * HEAD_DIM + d;
  bf16x8 v0 = *(const bf16x8*)&O0[src];
  bf16x8 v1 = *(const bf16x8*)&O1[src];
  u16 outv[8];
#pragma unroll
  for (int j = 0; j < 8; ++j)
    outv[j] = f2bf(w0 * bf2f((u16)v0[j]) + w1 * bf2f((u16)v1[j]));
  int bh = row >> 11, s = row & (SEQ - 1);
  size_t dst = ((size_t)(bh >> 4) * SEQ + s) * D_MODEL + (bh & 15) * HEAD_DIM + d;
  *(uint4*)&O[dst] = *(uint4*)outv;
}

// ---------------- launch ----------------
extern "C" void kernel_launch(void* const* d_in, const int* in_sizes, int n_in,
                              void* d_out, int out_size, void* d_ws, size_t ws_size,
                              hipStream_t stream) {
  const float* X = (const float*)d_in[0];
  const float* Wq = (const float*)d_in[1];
  const float* Wk = (const float*)d_in[2];
  const float* Wv = (const float*)d_in[3];
  const float* Wo = (const float*)d_in[4];
  float* OUT = (float*)d_out;
  char* ws = (char*)d_ws;

  u16* Xb = (u16*)(ws);                       // 16 MB (-> Ob after attn)
  u16* Wb0 = (u16*)(ws + (16u << 20));        // 4x8 MB
  u16* Wb1 = Wb0 + 4194304;
  u16* Wb2 = Wb1 + 4194304;
  u16* Wb3 = Wb2 + 4194304;
  u16* Qb = (u16*)(ws + (48u << 20));         // 16 MB
  u16* Kb = (u16*)(ws + (64u << 20));         // 16 MB
  u16* Vb = (u16*)(ws + (80u << 20));         // 16 MB
  u16* Vt = (u16*)(ws + (96u << 20));         // 16 MB
  float* cosT = (float*)(ws + (112u << 20));  // 512 KB
  float* sinT = cosT + SEQ * 64;              // 512 KB
  u16* Ob = Xb;                               // alias: Xb dead after gemm_qkv
  // split-attn partials in dead regions:
  u16* OpH0 = Vb;                             // Vb dead after vtrans (16 MB)
  u16* OpH1 = Wb0;                            // Wb0+Wb1 dead after gemm<0> (16 MB)
  float2* Ml = (float2*)Wb2;                  // Wb2 dead after gemm<0> (2 MB used)

  cast_bf16_kernel<<<8192, 256, 0, stream>>>(X, Xb, (M_ROWS * D_MODEL) / 4);
  cast_bf16_kernel<<<4096, 256, 0, stream>>>(Wq, Wb0, (D_MODEL * D_MODEL) / 4);
  cast_bf16_kernel<<<4096, 256, 0, stream>>>(Wk, Wb1, (D_MODEL * D_MODEL) / 4);
  cast_bf16_kernel<<<4096, 256, 0, stream>>>(Wv, Wb2, (D_MODEL * D_MODEL) / 4);
  cast_bf16_kernel<<<4096, 256, 0, stream>>>(Wo, Wb3, (D_MODEL * D_MODEL) / 4);
  rope_table_kernel<<<512, 256, 0, stream>>>(cosT, sinT);

  gemm_bt_kernel<0><<<dim3(32, 16, 3), 256, 0, stream>>>(Xb, Wb0, Wb1, Wb2, Qb, Kb, Vb, nullptr);
  rope_apply_kernel<<<dim3(16384, 2), 256, 0, stream>>>(Qb, Kb, cosT, sinT);
  vtrans_kernel<<<dim3(32, 2, 32), 256, 0, stream>>>(Vb, Vt);
  attn_split_kernel<<<dim3(32, 16, 2), 256, 0, stream>>>(Qb, Kb, Vt, OpH0, OpH1, Ml);
  attn_merge_kernel<<<4096, 256, 0, stream>>>(OpH0, OpH1, Ml, Ob);
  gemm_bt_kernel<1><<<dim3(32, 16, 1), 256, 0, stream>>>(Ob, Wb3, nullptr, nullptr, nullptr,
                                                         nullptr, nullptr, OUT);
}